// Round 1
// baseline (1002.115 us; speedup 1.0000x reference)
//
#include <hip/hip_runtime.h>
#include <stdint.h>

// ---------------------------------------------------------------------------
// Memory module forward:
//   1) nearest mem_point per query (packed u64 atomicMin -> (d2,idx))
//   2) 256 lowest-(usage,index) slots (hist -> threshold -> compact -> sort)
//   3) assign slots (mask = mind>1e-3), momentum bug => overwrite; virtualized
//      via bitmap + fixup list (inputs must not be modified)
//   4) masked cosine argmax over the 500k bank: f16 MFMA, HBM-bound 512MB read
//   5) finalize: fp32 fixup sims (self-match = 1.0 winner), gather outputs
// ---------------------------------------------------------------------------

typedef __attribute__((ext_vector_type(4))) float  float4_t;
typedef _Float16 half8 __attribute__((ext_vector_type(8)));

// ---- workspace layout (bytes) ----
#define WS_GMIN   0                       // 256 * u64
#define WS_CTRL   2048                    // [0]=ustar [1]=T [2]=kprime [3]=cnt
#define WS_HIST   4096                    // 64*1024 u32
#define WS_CAND   (4096 + 262144)         // 1024 u64
#define WS_LOWU   (266240 + 8192)         // 256 int
#define WS_FIDX   (274432 + 1024)         // 256 int
#define WS_WSRC   (275456 + 1024)         // 256 int
#define WS_XN     (276480 + 1024)         // 256 float
#define WS_BMP    (277504 + 1024)         // 16384 u32 bitmap (covers N<=524288)
#define WS_PART   (278528 + 65536)        // NB*256 float2

// ---------------------------------------------------------------------------
__global__ void k_init(uint32_t* __restrict__ hist, uint32_t* __restrict__ bmp,
                       unsigned long long* __restrict__ gmin, uint32_t* __restrict__ ctrl){
    int i = blockIdx.x * 256 + threadIdx.x;          // 65536 threads
    if (i < 65536) hist[i] = 0u;
    if (i < 16384) bmp[i] = 0u;
    if (i < 256)   gmin[i] = ~0ull;
    if (i < 8)     ctrl[i] = 0u;
}

// ---- 1) nearest point: each thread owns one query, blocks chunk the bank ----
__global__ void k_nearest(const float* __restrict__ pts, const float* __restrict__ mpts,
                          unsigned long long* __restrict__ gmin, int N){
    int t = threadIdx.x;                              // 256 threads = 256 queries
    float qx = pts[t*3+0], qy = pts[t*3+1], qz = pts[t*3+2];
    int chunk = (N + (int)gridDim.x - 1) / (int)gridDim.x;
    int lo = blockIdx.x * chunk;
    int hi = lo + chunk; if (hi > N) hi = N;
    unsigned long long best = ~0ull;
    #pragma unroll 4
    for (int n = lo; n < hi; ++n){
        float sx = mpts[3*n+0], sy = mpts[3*n+1], sz = mpts[3*n+2]; // uniform -> s_load
        float dx = qx - sx, dy = qy - sy, dz = qz - sz;
        float d2 = dx*dx + dy*dy + dz*dz;             // >=0 -> bits monotone
        unsigned long long key = ((unsigned long long)__float_as_uint(d2) << 32) | (unsigned)n;
        best = key < best ? key : best;               // tie -> lower index (jnp.argmin)
    }
    if (lo < hi) atomicMin(&gmin[t], best);
}

// ---- 2a) 2D histogram: clamped usage x index-bin ----
__global__ void k_hist(const int* __restrict__ usage, uint32_t* __restrict__ hist,
                       int N, int sh){
    int stride = (int)gridDim.x * (int)blockDim.x;
    for (int i = blockIdx.x * blockDim.x + threadIdx.x; i < N; i += stride){
        int u = usage[i]; u = u < 0 ? 0 : (u > 63 ? 63 : u);
        atomicAdd(&hist[u*1024 + (i >> sh)], 1u);
    }
}

// ---- 2b) find usage threshold u*, index threshold T ----
__global__ void k_select1(const uint32_t* __restrict__ hist, uint32_t* __restrict__ ctrl,
                          int sh, int Bq){
    __shared__ uint32_t ps[64*16];
    __shared__ uint32_t rsum[64];
    __shared__ uint32_t scan[1024];
    __shared__ uint32_t s_us, s_kp;
    int tid = threadIdx.x;                            // 1024 threads
    int u = tid >> 4, m = tid & 15;
    uint32_t p = 0;
    for (int c = 0; c < 64; ++c) p += hist[u*1024 + m + (c << 4)];
    ps[u*16 + m] = p;
    __syncthreads();
    if (tid < 64){
        uint32_t s = 0;
        for (int j = 0; j < 16; ++j) s += ps[tid*16 + j];
        rsum[tid] = s;
    }
    __syncthreads();
    if (tid == 0){
        uint32_t cum = 0, c0 = 0; int us = 63;
        for (int v = 0; v < 64; ++v){
            if (cum + rsum[v] >= (uint32_t)Bq){ us = v; c0 = cum; break; }
            cum += rsum[v];
        }
        s_us = (uint32_t)us; s_kp = (uint32_t)Bq - c0;
        ctrl[0] = (uint32_t)us; ctrl[2] = s_kp; ctrl[3] = 0u;
    }
    __syncthreads();
    uint32_t ustar = s_us, kp = s_kp;
    uint32_t v = hist[ustar*1024 + tid];
    scan[tid] = v; __syncthreads();
    for (int off = 1; off < 1024; off <<= 1){
        uint32_t add = (tid >= off) ? scan[tid - off] : 0u;
        __syncthreads();
        scan[tid] += add;
        __syncthreads();
    }
    uint32_t inc = scan[tid], exc = inc - v;
    if (inc >= kp && exc < kp) ctrl[1] = (uint32_t)((tid + 1) << sh);   // T
}

// ---- 2c) compact candidates (usage<u*) or (usage==u* && idx<T) ----
__global__ void k_collect(const int* __restrict__ usage, uint32_t* __restrict__ ctrl,
                          unsigned long long* __restrict__ cand, int N){
    int ustar = (int)ctrl[0]; uint32_t T = ctrl[1];
    int stride = (int)gridDim.x * (int)blockDim.x;
    for (int i = blockIdx.x * blockDim.x + threadIdx.x; i < N; i += stride){
        int u = usage[i]; int uc = u < 0 ? 0 : (u > 63 ? 63 : u);
        bool take = (uc < ustar) || (uc == ustar && (uint32_t)i < T);
        if (take){
            uint32_t pos = atomicAdd(&ctrl[3], 1u);
            if (pos < 1024u)
                cand[pos] = ((unsigned long long)(uint32_t)u << 32) | (uint32_t)i;
        }
    }
}

// ---- 2d) bitonic sort <=1024 candidate keys, emit 256 lowest slots ----
__global__ void k_sort(const uint32_t* __restrict__ ctrl,
                       unsigned long long* __restrict__ cand, int* __restrict__ lowu){
    __shared__ unsigned long long sk[1024];
    int tid = threadIdx.x;                            // 1024 threads
    uint32_t cnt = ctrl[3]; if (cnt > 1024u) cnt = 1024u;
    sk[tid] = (tid < (int)cnt) ? cand[tid] : ~0ull;
    __syncthreads();
    for (int k = 2; k <= 1024; k <<= 1)
        for (int j = k >> 1; j > 0; j >>= 1){
            int ixj = tid ^ j;
            if (ixj > tid){
                unsigned long long a = sk[tid], b = sk[ixj];
                bool up = ((tid & k) == 0);
                bool sw = up ? (a > b) : (a < b);
                if (sw){ sk[tid] = b; sk[ixj] = a; }
            }
            __syncthreads();
        }
    if (tid < 256) lowu[tid] = (int)(uint32_t)sk[tid];
}

// ---- 3) slot assignment, last-writer, bitmap, query norms ----
__global__ void k_assign(const float* __restrict__ desc,
                         const unsigned long long* __restrict__ gmin,
                         const int* __restrict__ lowu,
                         int* __restrict__ fidx, int* __restrict__ wsrc,
                         float* __restrict__ xn, uint32_t* __restrict__ bmp){
    __shared__ int sc[256];
    __shared__ int sidx[256];
    int b = threadIdx.x;                              // 256 threads
    unsigned long long key = gmin[b];
    float d2 = __uint_as_float((uint32_t)(key >> 32));
    int amin = (int)(uint32_t)key;
    int mask = (d2 > 1e-6f) ? 1 : 0;                  // mind>1e-3 <=> d2>1e-6
    sc[b] = mask; __syncthreads();
    for (int off = 1; off < 256; off <<= 1){          // inclusive scan
        int add = (b >= off) ? sc[b - off] : 0;
        __syncthreads();
        sc[b] += add;
        __syncthreads();
    }
    int rank = sc[b] - 1; rank = rank < 0 ? 0 : (rank > 255 ? 255 : rank);
    int fi = mask ? lowu[rank] : amin;
    sidx[b] = fi; __syncthreads();
    int lw = b;                                       // last writer of this slot
    for (int b2 = b + 1; b2 < 256; ++b2) if (sidx[b2] == fi) lw = b2;
    fidx[b] = fi; wsrc[b] = lw;
    atomicOr(&bmp[fi >> 5], 1u << (fi & 31));
    const float4_t* rp = (const float4_t*)(desc + b*256);
    float s = 0.f;
    #pragma unroll 8
    for (int i = 0; i < 64; ++i){
        float4_t v = rp[i];
        s += v[0]*v[0] + v[1]*v[1] + v[2]*v[2] + v[3]*v[3];
    }
    xn[b] = sqrtf(s);
}

// ---- 4) main pass: f16 MFMA cosine scores over non-overwritten slots ----
__global__ __launch_bounds__(256, 2) void k_main(
        const float* __restrict__ desc, const float* __restrict__ mdesc,
        const int* __restrict__ usage, const uint32_t* __restrict__ bmp,
        float2* __restrict__ part, int N){
    constexpr int PITCH = 260;                        // 256+4 floats: <=2-way LDS conflicts
    __shared__ float lds[16 * PITCH];
    __shared__ float s_sq[16 * 17];
    __shared__ float s_ryn[16];
    __shared__ float s_bias[16];
    int tid  = threadIdx.x;
    int wave = tid >> 6, lane = tid & 63;
    int l15  = lane & 15, q4 = lane >> 4;

    // persistent A-frags: wave owns queries [64w, 64w+64)
    half8 afrag[4][8];
    #pragma unroll
    for (int mt = 0; mt < 4; ++mt){
        int q = 64*wave + 16*mt + l15;
        const float* rowp = desc + q*256 + q4*8;
        #pragma unroll
        for (int k0 = 0; k0 < 8; ++k0){
            float4_t f0 = *(const float4_t*)(rowp + 32*k0);
            float4_t f1 = *(const float4_t*)(rowp + 32*k0 + 4);
            half8 h;
            h[0]=(_Float16)f0[0]; h[1]=(_Float16)f0[1]; h[2]=(_Float16)f0[2]; h[3]=(_Float16)f0[3];
            h[4]=(_Float16)f1[0]; h[5]=(_Float16)f1[1]; h[6]=(_Float16)f1[2]; h[7]=(_Float16)f1[3];
            afrag[mt][k0] = h;
        }
    }
    float runv[4][4]; uint32_t runi[4][4];
    #pragma unroll
    for (int a = 0; a < 4; ++a)
        #pragma unroll
        for (int r = 0; r < 4; ++r){ runv[a][r] = -3e38f; runi[a][r] = 0u; }

    int r = tid & 15, m = tid >> 4;
    int tiles = (N + 15) >> 4;
    for (int t = blockIdx.x; t < tiles; t += (int)gridDim.x){
        int slot0 = t << 4;
        int s = slot0 + r;
        __syncthreads();                              // protect LDS from prior readers
        float sq = 0.f;
        {
            const float* gp = mdesc + (size_t)s * 256 + m*16;
            float* lp = lds + r*PITCH + m*16;
            if (s < N){
                #pragma unroll
                for (int c = 0; c < 4; ++c){
                    float4_t v = *(const float4_t*)(gp + 4*c);
                    sq += v[0]*v[0] + v[1]*v[1] + v[2]*v[2] + v[3]*v[3];
                    *(float4_t*)(lp + 4*c) = v;
                }
            } else {
                #pragma unroll
                for (int c = 0; c < 4; ++c) *(float4_t*)(lp + 4*c) = (float4_t){0.f,0.f,0.f,0.f};
            }
        }
        s_sq[r*17 + m] = sq;
        __syncthreads();
        if (tid < 16){
            float tot = 0.f;
            #pragma unroll
            for (int j = 0; j < 16; ++j) tot += s_sq[tid*17 + j];
            int ss = slot0 + tid;
            bool valid = (ss < N) && (usage[ss] > 0) && !((bmp[ss >> 5] >> (ss & 31)) & 1u);
            s_ryn[tid]  = (ss < N) ? rsqrtf(fmaxf(tot, 1e-30f)) : 0.f;
            s_bias[tid] = valid ? 0.f : -1e30f;
        }
        __syncthreads();

        float4_t acc[4];
        #pragma unroll
        for (int a = 0; a < 4; ++a) acc[a] = (float4_t){0.f,0.f,0.f,0.f};
        const float* bp = lds + l15*PITCH + q4*8;
        #pragma unroll
        for (int k0 = 0; k0 < 8; ++k0){
            float4_t b0 = *(const float4_t*)(bp + 32*k0);
            float4_t b1 = *(const float4_t*)(bp + 32*k0 + 4);
            half8 hb;
            hb[0]=(_Float16)b0[0]; hb[1]=(_Float16)b0[1]; hb[2]=(_Float16)b0[2]; hb[3]=(_Float16)b0[3];
            hb[4]=(_Float16)b1[0]; hb[5]=(_Float16)b1[1]; hb[6]=(_Float16)b1[2]; hb[7]=(_Float16)b1[3];
            #pragma unroll
            for (int mt = 0; mt < 4; ++mt)
                acc[mt] = __builtin_amdgcn_mfma_f32_16x16x32_f16(afrag[mt][k0], hb, acc[mt], 0, 0, 0);
        }
        float ryn  = s_ryn[l15];
        float bias = s_bias[l15];
        uint32_t sidx = (uint32_t)(slot0 + l15);
        #pragma unroll
        for (int mt = 0; mt < 4; ++mt)
            #pragma unroll
            for (int rr = 0; rr < 4; ++rr){
                float val = acc[mt][rr] * ryn + bias;
                if (val > runv[mt][rr]){ runv[mt][rr] = val; runi[mt][rr] = sidx; }
            }
    }
    // reduce over the 16 slot-lanes (same q4 group); tie -> lower slot index
    #pragma unroll
    for (int mt = 0; mt < 4; ++mt)
        #pragma unroll
        for (int rr = 0; rr < 4; ++rr){
            float v = runv[mt][rr]; uint32_t ix = runi[mt][rr];
            for (int off = 1; off < 16; off <<= 1){
                float vo   = __shfl_xor(v, off, 64);
                uint32_t io = (uint32_t)__shfl_xor((int)ix, off, 64);
                if (vo > v || (vo == v && io < ix)){ v = vo; ix = io; }
            }
            if (l15 == 0){
                int q = 64*wave + 16*mt + q4*4 + rr;
                part[(size_t)blockIdx.x * 256 + q] = make_float2(v, __uint_as_float(ix));
            }
        }
}

// ---- 5) finalize: fixup sims (fp32), combine, gather outputs ----
__global__ void k_fin(const float* __restrict__ desc, const float* __restrict__ mdesc,
                      const float2* __restrict__ part, const int* __restrict__ fidx,
                      const int* __restrict__ wsrc, const float* __restrict__ xn,
                      float* __restrict__ out, int N, int NB){
    __shared__ float rv[256]; __shared__ int ri[256]; __shared__ int rs[256];
    int q = blockIdx.x, tid = threadIdx.x;
    int s_j = fidx[tid], r_j = wsrc[tid];
    const float4_t* qa = (const float4_t*)(desc + q*256);
    const float4_t* ra = (const float4_t*)(desc + r_j*256);
    float dot = 0.f;
    #pragma unroll 8
    for (int i = 0; i < 64; ++i){
        float4_t a = qa[i], b = ra[i];
        dot += a[0]*b[0] + a[1]*b[1] + a[2]*b[2] + a[3]*b[3];
    }
    float xq = xn[q];
    float bv = dot / fmaxf(xq * xn[r_j], 1e-7f);      // exact reference formula
    int bi = s_j, bs = r_j;
    float rxn = 1.f / xq;                             // deferred query-norm scale
    for (int p = tid; p < NB; p += 256){
        float2 e = part[(size_t)p * 256 + q];
        float val = e.x * rxn;
        int idx = (int)__float_as_uint(e.y);
        if (val > bv || (val == bv && idx < bi)){ bv = val; bi = idx; bs = -1; }
    }
    rv[tid] = bv; ri[tid] = bi; rs[tid] = bs;
    __syncthreads();
    for (int s = 128; s > 0; s >>= 1){
        if (tid < s){
            float v2 = rv[tid + s]; int i2 = ri[tid + s];
            if (v2 > rv[tid] || (v2 == rv[tid] && i2 < ri[tid])){
                rv[tid] = v2; ri[tid] = i2; rs[tid] = rs[tid + s];
            }
        }
        __syncthreads();
    }
    float win_v = rv[0]; int win_i = ri[0]; int win_s = rs[0];
    const float* wrow = desc + wsrc[q]*256;
    const float* rrow = (win_s >= 0) ? (desc + win_s*256) : (mdesc + (size_t)win_i * 256);
    size_t ob = (size_t)q * 513;
    out[ob + tid]       = wrow[tid];
    out[ob + 256 + tid] = rrow[tid];
    if (tid == 0) out[ob + 512] = win_v;
}

// ---------------------------------------------------------------------------
extern "C" void kernel_launch(void* const* d_in, const int* in_sizes, int n_in,
                              void* d_out, int out_size, void* d_ws, size_t ws_size,
                              hipStream_t stream){
    const float* pts   = (const float*)d_in[0];
    const float* desc  = (const float*)d_in[1];
    const float* mpts  = (const float*)d_in[2];
    const float* mdesc = (const float*)d_in[3];
    const int*   usage = (const int*)d_in[4];
    int N = in_sizes[4];

    char* ws = (char*)d_ws;
    unsigned long long* gmin = (unsigned long long*)(ws + WS_GMIN);
    uint32_t* ctrl = (uint32_t*)(ws + WS_CTRL);
    uint32_t* hist = (uint32_t*)(ws + WS_HIST);
    unsigned long long* cand = (unsigned long long*)(ws + WS_CAND);
    int*   lowu = (int*)(ws + WS_LOWU);
    int*   fidx = (int*)(ws + WS_FIDX);
    int*   wsrc = (int*)(ws + WS_WSRC);
    float* xn   = (float*)(ws + WS_XN);
    uint32_t* bmp = (uint32_t*)(ws + WS_BMP);
    float2* part  = (float2*)(ws + WS_PART);

    int sh = 9; while (((N - 1) >> sh) >= 1024) ++sh;
    int tiles = (N + 15) >> 4;
    int NB = 512;
    if (ws_size > (size_t)WS_PART){
        size_t avail = (ws_size - (size_t)WS_PART) / (256 * sizeof(float2));
        if ((size_t)NB > avail) NB = (int)avail;
    }
    if (NB > tiles) NB = tiles;
    if (NB < 1) NB = 1;

    k_init   <<<256, 256, 0, stream>>>(hist, bmp, gmin, ctrl);
    k_nearest<<<512, 256, 0, stream>>>(pts, mpts, gmin, N);
    k_hist   <<<1024, 256, 0, stream>>>(usage, hist, N, sh);
    k_select1<<<1, 1024, 0, stream>>>(hist, ctrl, sh, 256);
    k_collect<<<1024, 256, 0, stream>>>(usage, ctrl, cand, N);
    k_sort   <<<1, 1024, 0, stream>>>(ctrl, cand, lowu);
    k_assign <<<1, 256, 0, stream>>>(desc, gmin, lowu, fidx, wsrc, xn, bmp);
    k_main   <<<NB, 256, 0, stream>>>(desc, mdesc, usage, bmp, part, N);
    k_fin    <<<256, 256, 0, stream>>>(desc, mdesc, part, fidx, wsrc, xn,
                                       (float*)d_out, N, NB);
}

// Round 2
// 808.056 us; speedup vs baseline: 1.2402x; 1.2402x over previous
//
#include <hip/hip_runtime.h>
#include <stdint.h>

// ---------------------------------------------------------------------------
// Memory module forward:
//   1) nearest mem_point per query (packed u64 atomicMin -> (d2,idx))
//   2) 256 lowest-(usage,index) slots (hist -> threshold -> compact -> sort)
//   3) assign slots (mask = mind>1e-3), momentum bug => overwrite; virtualized
//      via bitmap + fixup list (inputs must not be modified)
//   4) masked cosine argmax over the 500k bank: LDS-free, barrier-free f16
//      MFMA with B-frags loaded straight from global (one tile per wave)
//   5) finalize: fp32 fixup sims (self-match = 1.0 winner), gather outputs
// ---------------------------------------------------------------------------

typedef __attribute__((ext_vector_type(4))) float  float4_t;
typedef _Float16 half8 __attribute__((ext_vector_type(8)));

// ---- workspace layout (bytes) ----
#define WS_GMIN   0                       // 256 * u64
#define WS_CTRL   2048                    // [0]=ustar [1]=T [2]=kprime [3]=cnt
#define WS_HIST   4096                    // 64*1024 u32
#define WS_CAND   (4096 + 262144)         // 1024 u64
#define WS_LOWU   (266240 + 8192)         // 256 int
#define WS_FIDX   (274432 + 1024)         // 256 int
#define WS_WSRC   (275456 + 1024)         // 256 int
#define WS_XN     (276480 + 1024)         // 256 float
#define WS_BMP    (277504 + 1024)         // 16384 u32 bitmap (covers N<=524288)
#define WS_PART   (278528 + 65536)        // NW*256 float2  (part[q][W])

// ---------------------------------------------------------------------------
__global__ void k_init(uint32_t* __restrict__ hist, uint32_t* __restrict__ bmp,
                       unsigned long long* __restrict__ gmin, uint32_t* __restrict__ ctrl){
    int i = blockIdx.x * 256 + threadIdx.x;          // 65536 threads
    if (i < 65536) hist[i] = 0u;
    if (i < 16384) bmp[i] = 0u;
    if (i < 256)   gmin[i] = ~0ull;
    if (i < 8)     ctrl[i] = 0u;
}

// ---- 1) nearest point: each thread owns one query, blocks chunk the bank ----
__global__ void k_nearest(const float* __restrict__ pts, const float* __restrict__ mpts,
                          unsigned long long* __restrict__ gmin, int N){
    int t = threadIdx.x;                              // 256 threads = 256 queries
    float qx = pts[t*3+0], qy = pts[t*3+1], qz = pts[t*3+2];
    int chunk = (N + (int)gridDim.x - 1) / (int)gridDim.x;
    int lo = blockIdx.x * chunk;
    int hi = lo + chunk; if (hi > N) hi = N;
    unsigned long long best = ~0ull;
    #pragma unroll 4
    for (int n = lo; n < hi; ++n){
        float sx = mpts[3*n+0], sy = mpts[3*n+1], sz = mpts[3*n+2]; // uniform -> s_load
        float dx = qx - sx, dy = qy - sy, dz = qz - sz;
        float d2 = dx*dx + dy*dy + dz*dz;             // >=0 -> bits monotone
        unsigned long long key = ((unsigned long long)__float_as_uint(d2) << 32) | (unsigned)n;
        best = key < best ? key : best;               // tie -> lower index (jnp.argmin)
    }
    if (lo < hi) atomicMin(&gmin[t], best);
}

// ---- 2a) 2D histogram: clamped usage x index-bin, wave-aggregated atomics ----
__global__ void k_hist(const int* __restrict__ usage, uint32_t* __restrict__ hist,
                       int N, int sh){
    int stride = (int)gridDim.x * (int)blockDim.x;
    int lane = threadIdx.x & 63;
    for (int base = blockIdx.x * blockDim.x; base < N; base += stride){
        int i = base + (int)threadIdx.x;
        bool ok = i < N;
        int u = 0, bin = 0;
        if (ok){
            u = usage[i]; u = u < 0 ? 0 : (u > 63 ? 63 : u);
            bin = i >> sh;
        }
        unsigned long long rem = __ballot(ok);
        while (rem){
            int leader = __ffsll(rem) - 1;
            int lu = __shfl(u,   leader, 64);
            int lb = __shfl(bin, leader, 64);
            unsigned long long match = __ballot(ok && u == lu && bin == lb) & rem;
            if (lane == leader)
                atomicAdd(&hist[lu*1024 + lb], (uint32_t)__popcll(match));
            rem &= ~match;
        }
    }
}

// ---- 2b) find usage threshold u*, index threshold T ----
__global__ void k_select1(const uint32_t* __restrict__ hist, uint32_t* __restrict__ ctrl,
                          int sh, int Bq){
    __shared__ uint32_t ps[64*16];
    __shared__ uint32_t rsum[64];
    __shared__ uint32_t scan[1024];
    __shared__ uint32_t s_us, s_kp;
    int tid = threadIdx.x;                            // 1024 threads
    int u = tid >> 4, m = tid & 15;
    uint32_t p = 0;
    for (int c = 0; c < 64; ++c) p += hist[u*1024 + m + (c << 4)];
    ps[u*16 + m] = p;
    __syncthreads();
    if (tid < 64){
        uint32_t s = 0;
        for (int j = 0; j < 16; ++j) s += ps[tid*16 + j];
        rsum[tid] = s;
    }
    __syncthreads();
    if (tid == 0){
        uint32_t cum = 0, c0 = 0; int us = 63;
        for (int v = 0; v < 64; ++v){
            if (cum + rsum[v] >= (uint32_t)Bq){ us = v; c0 = cum; break; }
            cum += rsum[v];
        }
        s_us = (uint32_t)us; s_kp = (uint32_t)Bq - c0;
        ctrl[0] = (uint32_t)us; ctrl[2] = s_kp; ctrl[3] = 0u;
    }
    __syncthreads();
    uint32_t ustar = s_us, kp = s_kp;
    uint32_t v = hist[ustar*1024 + tid];
    scan[tid] = v; __syncthreads();
    for (int off = 1; off < 1024; off <<= 1){
        uint32_t add = (tid >= off) ? scan[tid - off] : 0u;
        __syncthreads();
        scan[tid] += add;
        __syncthreads();
    }
    uint32_t inc = scan[tid], exc = inc - v;
    if (inc >= kp && exc < kp) ctrl[1] = (uint32_t)((tid + 1) << sh);   // T
}

// ---- 2c) compact candidates (usage<u*) or (usage==u* && idx<T) ----
__global__ void k_collect(const int* __restrict__ usage, uint32_t* __restrict__ ctrl,
                          unsigned long long* __restrict__ cand, int N){
    int ustar = (int)ctrl[0]; uint32_t T = ctrl[1];
    int stride = (int)gridDim.x * (int)blockDim.x;
    for (int i = blockIdx.x * blockDim.x + threadIdx.x; i < N; i += stride){
        int u = usage[i]; int uc = u < 0 ? 0 : (u > 63 ? 63 : u);
        bool take = (uc < ustar) || (uc == ustar && (uint32_t)i < T);
        if (take){
            uint32_t pos = atomicAdd(&ctrl[3], 1u);
            if (pos < 1024u)
                cand[pos] = ((unsigned long long)(uint32_t)u << 32) | (uint32_t)i;
        }
    }
}

// ---- 2d) bitonic sort <=1024 candidate keys, emit 256 lowest slots ----
__global__ void k_sort(const uint32_t* __restrict__ ctrl,
                       unsigned long long* __restrict__ cand, int* __restrict__ lowu){
    __shared__ unsigned long long sk[1024];
    int tid = threadIdx.x;                            // 1024 threads
    uint32_t cnt = ctrl[3]; if (cnt > 1024u) cnt = 1024u;
    sk[tid] = (tid < (int)cnt) ? cand[tid] : ~0ull;
    __syncthreads();
    for (int k = 2; k <= 1024; k <<= 1)
        for (int j = k >> 1; j > 0; j >>= 1){
            int ixj = tid ^ j;
            if (ixj > tid){
                unsigned long long a = sk[tid], b = sk[ixj];
                bool up = ((tid & k) == 0);
                bool sw = up ? (a > b) : (a < b);
                if (sw){ sk[tid] = b; sk[ixj] = a; }
            }
            __syncthreads();
        }
    if (tid < 256) lowu[tid] = (int)(uint32_t)sk[tid];
}

// ---- 3) slot assignment, last-writer, bitmap, query norms ----
__global__ void k_assign(const float* __restrict__ desc,
                         const unsigned long long* __restrict__ gmin,
                         const int* __restrict__ lowu,
                         int* __restrict__ fidx, int* __restrict__ wsrc,
                         float* __restrict__ xn, uint32_t* __restrict__ bmp){
    __shared__ int sc[256];
    __shared__ int sidx[256];
    int b = threadIdx.x;                              // 256 threads
    unsigned long long key = gmin[b];
    float d2 = __uint_as_float((uint32_t)(key >> 32));
    int amin = (int)(uint32_t)key;
    int mask = (d2 > 1e-6f) ? 1 : 0;                  // mind>1e-3 <=> d2>1e-6
    sc[b] = mask; __syncthreads();
    for (int off = 1; off < 256; off <<= 1){          // inclusive scan
        int add = (b >= off) ? sc[b - off] : 0;
        __syncthreads();
        sc[b] += add;
        __syncthreads();
    }
    int rank = sc[b] - 1; rank = rank < 0 ? 0 : (rank > 255 ? 255 : rank);
    int fi = mask ? lowu[rank] : amin;
    sidx[b] = fi; __syncthreads();
    int lw = b;                                       // last writer of this slot
    for (int b2 = b + 1; b2 < 256; ++b2) if (sidx[b2] == fi) lw = b2;
    fidx[b] = fi; wsrc[b] = lw;
    atomicOr(&bmp[fi >> 5], 1u << (fi & 31));
    const float4_t* rp = (const float4_t*)(desc + b*256);
    float s = 0.f;
    #pragma unroll 8
    for (int i = 0; i < 64; ++i){
        float4_t v = rp[i];
        s += v[0]*v[0] + v[1]*v[1] + v[2]*v[2] + v[3]*v[3];
    }
    xn[b] = sqrtf(s);
}

// ---- 4) main pass: LDS-free, barrier-free f16 MFMA; one 16-slot tile/wave ----
__global__ __launch_bounds__(256, 2) void k_main(
        const float* __restrict__ desc, const float* __restrict__ mdesc,
        const int* __restrict__ usage, const uint32_t* __restrict__ bmp,
        float2* __restrict__ part, int N, int NW){
    int tid  = threadIdx.x;
    int wave = tid >> 6, lane = tid & 63;
    int l15  = lane & 15, q4 = lane >> 4;
    int W = blockIdx.x * 4 + wave;                    // global wave id

    // persistent A-frags: wave owns queries [64w, 64w+64)
    half8 afrag[4][8];
    #pragma unroll
    for (int mt = 0; mt < 4; ++mt){
        int q = 64*wave + 16*mt + l15;
        const float* rowp = desc + q*256 + q4*8;
        #pragma unroll
        for (int k0 = 0; k0 < 8; ++k0){
            float4_t f0 = *(const float4_t*)(rowp + 32*k0);
            float4_t f1 = *(const float4_t*)(rowp + 32*k0 + 4);
            half8 h;
            h[0]=(_Float16)f0[0]; h[1]=(_Float16)f0[1]; h[2]=(_Float16)f0[2]; h[3]=(_Float16)f0[3];
            h[4]=(_Float16)f1[0]; h[5]=(_Float16)f1[1]; h[6]=(_Float16)f1[2]; h[7]=(_Float16)f1[3];
            afrag[mt][k0] = h;
        }
    }
    float runv[4][4]; uint32_t runi[4][4];
    #pragma unroll
    for (int a = 0; a < 4; ++a)
        #pragma unroll
        for (int r = 0; r < 4; ++r){ runv[a][r] = -3e38f; runi[a][r] = 0u; }

    int tiles = (N + 15) >> 4;
    // B-frag layout straight from global: lane (l15,q4) reads row slot0+l15,
    // dwords [q4*8 + 32*k0, +8). Immediate offsets cover k0 (128B steps < 4KB).
    const float* pb = mdesc + (size_t)l15 * 256 + q4 * 8 + (size_t)W * (16 * 256);
    size_t tstep = (size_t)NW * (16 * 256);

    for (int t = W; t < tiles; t += NW){
        int s = (t << 4) + l15;
        bool sok = s < N;
        int uval = sok ? usage[s] : 0;                // early: ready by epilogue
        uint32_t bw = sok ? bmp[s >> 5] : 0u;
        const float* pc = pb; pb += tstep;            // advance early (prefetch)
        float sq = 0.f;
        float4_t acc[4];
        #pragma unroll
        for (int a = 0; a < 4; ++a) acc[a] = (float4_t){0.f,0.f,0.f,0.f};
        #pragma unroll
        for (int k0 = 0; k0 < 8; ++k0){
            float4_t b0, b1;
            if (sok){
                b0 = *(const float4_t*)(pc + 32*k0);
                b1 = *(const float4_t*)(pc + 32*k0 + 4);
            } else {
                b0 = (float4_t){0.f,0.f,0.f,0.f};
                b1 = (float4_t){0.f,0.f,0.f,0.f};
            }
            sq += b0[0]*b0[0] + b0[1]*b0[1] + b0[2]*b0[2] + b0[3]*b0[3]
                + b1[0]*b1[0] + b1[1]*b1[1] + b1[2]*b1[2] + b1[3]*b1[3];
            half8 hb;
            hb[0]=(_Float16)b0[0]; hb[1]=(_Float16)b0[1]; hb[2]=(_Float16)b0[2]; hb[3]=(_Float16)b0[3];
            hb[4]=(_Float16)b1[0]; hb[5]=(_Float16)b1[1]; hb[6]=(_Float16)b1[2]; hb[7]=(_Float16)b1[3];
            #pragma unroll
            for (int mt = 0; mt < 4; ++mt)
                acc[mt] = __builtin_amdgcn_mfma_f32_16x16x32_f16(afrag[mt][k0], hb, acc[mt], 0, 0, 0);
        }
        // slot norm^2: lane holds 1/4 of row l15; sum over the 4 q4-groups
        sq += __shfl_xor(sq, 16, 64);
        sq += __shfl_xor(sq, 32, 64);
        float ryn = rsqrtf(fmaxf(sq, 1e-30f));
        bool valid = sok && (uval > 0) && !((bw >> (s & 31)) & 1u);
        float bias = valid ? 0.f : -1e30f;
        uint32_t sidx = (uint32_t)s;
        #pragma unroll
        for (int mt = 0; mt < 4; ++mt)
            #pragma unroll
            for (int rr = 0; rr < 4; ++rr){
                float val = acc[mt][rr] * ryn + bias;
                if (val > runv[mt][rr]){ runv[mt][rr] = val; runi[mt][rr] = sidx; }
            }
    }
    // reduce over the 16 slot-lanes (same q4 group); tie -> lower slot index
    #pragma unroll
    for (int mt = 0; mt < 4; ++mt)
        #pragma unroll
        for (int rr = 0; rr < 4; ++rr){
            float v = runv[mt][rr]; uint32_t ix = runi[mt][rr];
            for (int off = 1; off < 16; off <<= 1){
                float vo   = __shfl_xor(v, off, 64);
                uint32_t io = (uint32_t)__shfl_xor((int)ix, off, 64);
                if (vo > v || (vo == v && io < ix)){ v = vo; ix = io; }
            }
            if (l15 == 0){
                int q = 64*wave + 16*mt + q4*4 + rr;
                part[(size_t)q * NW + W] = make_float2(v, __uint_as_float(ix));
            }
        }
}

// ---- 5) finalize: fixup sims (fp32), combine, gather outputs ----
__global__ void k_fin(const float* __restrict__ desc, const float* __restrict__ mdesc,
                      const float2* __restrict__ part, const int* __restrict__ fidx,
                      const int* __restrict__ wsrc, const float* __restrict__ xn,
                      float* __restrict__ out, int N, int NW){
    __shared__ float rv[256]; __shared__ int ri[256]; __shared__ int rs[256];
    int q = blockIdx.x, tid = threadIdx.x;
    int s_j = fidx[tid], r_j = wsrc[tid];
    const float4_t* qa = (const float4_t*)(desc + q*256);
    const float4_t* ra = (const float4_t*)(desc + r_j*256);
    float dot = 0.f;
    #pragma unroll 8
    for (int i = 0; i < 64; ++i){
        float4_t a = qa[i], b = ra[i];
        dot += a[0]*b[0] + a[1]*b[1] + a[2]*b[2] + a[3]*b[3];
    }
    float xq = xn[q];
    float bv = dot / fmaxf(xq * xn[r_j], 1e-7f);      // exact reference formula
    int bi = s_j, bs = r_j;
    float rxn = 1.f / xq;                             // deferred query-norm scale
    for (int p = tid; p < NW; p += 256){
        float2 e = part[(size_t)q * NW + p];          // coalesced: contiguous p
        float val = e.x * rxn;
        int idx = (int)__float_as_uint(e.y);
        if (val > bv || (val == bv && idx < bi)){ bv = val; bi = idx; bs = -1; }
    }
    rv[tid] = bv; ri[tid] = bi; rs[tid] = bs;
    __syncthreads();
    for (int s = 128; s > 0; s >>= 1){
        if (tid < s){
            float v2 = rv[tid + s]; int i2 = ri[tid + s];
            if (v2 > rv[tid] || (v2 == rv[tid] && i2 < ri[tid])){
                rv[tid] = v2; ri[tid] = i2; rs[tid] = rs[tid + s];
            }
        }
        __syncthreads();
    }
    float win_v = rv[0]; int win_i = ri[0]; int win_s = rs[0];
    const float* wrow = desc + wsrc[q]*256;
    const float* rrow = (win_s >= 0) ? (desc + win_s*256) : (mdesc + (size_t)win_i * 256);
    size_t ob = (size_t)q * 513;
    out[ob + tid]       = wrow[tid];
    out[ob + 256 + tid] = rrow[tid];
    if (tid == 0) out[ob + 512] = win_v;
}

// ---------------------------------------------------------------------------
extern "C" void kernel_launch(void* const* d_in, const int* in_sizes, int n_in,
                              void* d_out, int out_size, void* d_ws, size_t ws_size,
                              hipStream_t stream){
    const float* pts   = (const float*)d_in[0];
    const float* desc  = (const float*)d_in[1];
    const float* mpts  = (const float*)d_in[2];
    const float* mdesc = (const float*)d_in[3];
    const int*   usage = (const int*)d_in[4];
    int N = in_sizes[4];

    char* ws = (char*)d_ws;
    unsigned long long* gmin = (unsigned long long*)(ws + WS_GMIN);
    uint32_t* ctrl = (uint32_t*)(ws + WS_CTRL);
    uint32_t* hist = (uint32_t*)(ws + WS_HIST);
    unsigned long long* cand = (unsigned long long*)(ws + WS_CAND);
    int*   lowu = (int*)(ws + WS_LOWU);
    int*   fidx = (int*)(ws + WS_FIDX);
    int*   wsrc = (int*)(ws + WS_WSRC);
    float* xn   = (float*)(ws + WS_XN);
    uint32_t* bmp = (uint32_t*)(ws + WS_BMP);
    float2* part  = (float2*)(ws + WS_PART);

    int sh = 9; while (((N - 1) >> sh) >= 1024) ++sh;

    // 2048 waves = 512 blocks = 2 blocks/CU (VGPR-limited occupancy for k_main)
    int NW = 2048;
    while (NW > 8 && (size_t)WS_PART + (size_t)NW * 256 * sizeof(float2) > ws_size)
        NW >>= 1;
    int nb_main = NW / 4;

    k_init   <<<256, 256, 0, stream>>>(hist, bmp, gmin, ctrl);
    k_nearest<<<1024, 256, 0, stream>>>(pts, mpts, gmin, N);
    k_hist   <<<1024, 256, 0, stream>>>(usage, hist, N, sh);
    k_select1<<<1, 1024, 0, stream>>>(hist, ctrl, sh, 256);
    k_collect<<<1024, 256, 0, stream>>>(usage, ctrl, cand, N);
    k_sort   <<<1, 1024, 0, stream>>>(ctrl, cand, lowu);
    k_assign <<<1, 256, 0, stream>>>(desc, gmin, lowu, fidx, wsrc, xn, bmp);
    k_main   <<<nb_main, 256, 0, stream>>>(desc, mdesc, usage, bmp, part, N, NW);
    k_fin    <<<256, 256, 0, stream>>>(desc, mdesc, part, fidx, wsrc, xn,
                                       (float*)d_out, N, NW);
}